// Round 12
// baseline (271.440 us; speedup 1.0000x reference)
//
#include <hip/hip_runtime.h>
#include <hip/hip_bf16.h>

#define BB 8
#define SS 512
#define HIDV 768
#define HH 12
#define DD 64
#define LV 81

typedef __attribute__((ext_vector_type(8))) short short8v;
typedef __attribute__((ext_vector_type(4))) short short4v;
typedef __attribute__((ext_vector_type(4))) float f32x4;

#define MFMA16(a, b, c) __builtin_amdgcn_mfma_f32_16x16x32_bf16(a, b, c, 0, 0, 0)

__device__ __forceinline__ short f2bf(float f) {
    __hip_bfloat16 h = __float2bfloat16(f);
    return *reinterpret_cast<short*>(&h);
}
__device__ __forceinline__ short f2h(float f) {
    _Float16 h = (_Float16)f; short s; __builtin_memcpy(&s, &h, 2); return s;
}
__device__ __forceinline__ float h2f(short s) {
    _Float16 h; __builtin_memcpy(&h, &s, 2); return (float)h;
}
__device__ __forceinline__ void gload16(const void* g, void* l) {
    __builtin_amdgcn_global_load_lds((const __attribute__((address_space(1))) void*)g,
                                     (__attribute__((address_space(3))) void*)l, 16, 0, 0);
}

// ---------------- LN tables -> lnkb bf16 [96][64], lnvT96 bf16 [64][96] ----------------
__global__ __launch_bounds__(256) void prep_ln_kernel(
    const float* __restrict__ rel_k, const float* __restrict__ rel_v,
    const float* __restrict__ gk, const float* __restrict__ bk,
    const float* __restrict__ gv, const float* __restrict__ bv,
    short* __restrict__ lnkb, short* __restrict__ lnvT96) {
    __shared__ float ln_lds[2 * LV][DD];
    int t = threadIdx.x;
    if (t < 2 * LV) {
        bool isv = (t >= LV);
        int r = isv ? t - LV : t;
        const float* row = (isv ? rel_v : rel_k) + r * DD;
        const float* g = isv ? gv : gk;
        const float* be = isv ? bv : bk;
        float mu = 0.f;
        for (int d = 0; d < DD; ++d) mu += row[d];
        mu *= (1.f / DD);
        float var = 0.f;
        for (int d = 0; d < DD; ++d) { float x = row[d] - mu; var += x * x; }
        var *= (1.f / DD);
        float rs = rsqrtf(var + 1e-5f);
        for (int d = 0; d < DD; ++d) ln_lds[t][d] = (row[d] - mu) * rs * g[d] + be[d];
    }
    __syncthreads();
    for (int i = t; i < 96 * DD; i += 256) {
        int l = i >> 6, d = i & 63;
        lnkb[i] = (l < LV) ? f2bf(ln_lds[l][d]) : (short)0;
    }
    for (int i = t; i < DD * 96; i += 256) {
        int d = i / 96, ll = i - d * 96;
        lnvT96[i] = (ll < LV) ? f2bf(ln_lds[LV + ll][d]) : (short)0;
    }
}

// ---------------- hidden f32 -> bf16 ----------------
__global__ __launch_bounds__(256) void conv_hidden_kernel(const float* __restrict__ in,
                                                          short* __restrict__ out) {
    int i = (blockIdx.x * 256 + threadIdx.x) * 4;
    float4 v = *reinterpret_cast<const float4*>(&in[i]);
    short4v o; o[0] = f2bf(v.x); o[1] = f2bf(v.y); o[2] = f2bf(v.z); o[3] = f2bf(v.w);
    *reinterpret_cast<short4v*>(&out[i]) = o;
}

// ---------------- W [k][n] f32 -> WT [n][k] bf16 (x3 via z) ----------------
__global__ __launch_bounds__(256) void transw_kernel(
    const float* __restrict__ Wq, const float* __restrict__ Wk, const float* __restrict__ Wv,
    short* __restrict__ WqT, short* __restrict__ WkT, short* __restrict__ WvT) {
    const float* W; short* O;
    if (blockIdx.z == 0) { W = Wq; O = WqT; }
    else if (blockIdx.z == 1) { W = Wk; O = WkT; }
    else { W = Wv; O = WvT; }
    __shared__ float tile[32][33];
    int k0 = blockIdx.y * 32, n0 = blockIdx.x * 32;
    int t = threadIdx.x;
    int r = t >> 3, c4 = (t & 7) * 4;
    float4 v = *reinterpret_cast<const float4*>(&W[(size_t)(k0 + r) * HIDV + n0 + c4]);
    tile[r][c4 + 0] = v.x; tile[r][c4 + 1] = v.y; tile[r][c4 + 2] = v.z; tile[r][c4 + 3] = v.w;
    __syncthreads();
    short4v o;
    o[0] = f2bf(tile[c4 + 0][r]); o[1] = f2bf(tile[c4 + 1][r]);
    o[2] = f2bf(tile[c4 + 2][r]); o[3] = f2bf(tile[c4 + 3][r]);
    *reinterpret_cast<short4v*>(&O[(size_t)(n0 + r) * HIDV + k0 + c4]) = o;
}

// ---------------- arc int32 -> u8 (same layout, packed) ----------------
__global__ __launch_bounds__(256) void arc8_kernel(const int* __restrict__ arc,
                                                   unsigned char* __restrict__ a8) {
    size_t base = ((size_t)blockIdx.x * 256 + threadIdx.x) * 16;
    int4 v0 = *reinterpret_cast<const int4*>(&arc[base]);
    int4 v1 = *reinterpret_cast<const int4*>(&arc[base + 4]);
    int4 v2 = *reinterpret_cast<const int4*>(&arc[base + 8]);
    int4 v3 = *reinterpret_cast<const int4*>(&arc[base + 12]);
    uint4 o;
    o.x = (unsigned)(v0.x & 255) | ((unsigned)(v0.y & 255) << 8) |
          ((unsigned)(v0.z & 255) << 16) | ((unsigned)(v0.w & 255) << 24);
    o.y = (unsigned)(v1.x & 255) | ((unsigned)(v1.y & 255) << 8) |
          ((unsigned)(v1.z & 255) << 16) | ((unsigned)(v1.w & 255) << 24);
    o.z = (unsigned)(v2.x & 255) | ((unsigned)(v2.y & 255) << 8) |
          ((unsigned)(v2.z & 255) << 16) | ((unsigned)(v2.w & 255) << 24);
    o.w = (unsigned)(v3.x & 255) | ((unsigned)(v3.y & 255) << 8) |
          ((unsigned)(v3.z & 255) << 16) | ((unsigned)(v3.w & 255) << 24);
    *reinterpret_cast<uint4*>(&a8[base]) = o;
}

// ---------------- QKV GEMM bf16 MFMA (unchanged, proven) ----------------
__global__ __launch_bounds__(256) void qkv_gemm_kernel(
    const short* __restrict__ Abf,
    const short* __restrict__ WqT, const short* __restrict__ WkT, const short* __restrict__ WvT,
    const float* __restrict__ bq, const float* __restrict__ bk, const float* __restrict__ bv,
    short* __restrict__ qo, short* __restrict__ ko, short* __restrict__ vto) {
    const short* Bt; const float* bias;
    int z = blockIdx.z;
    if (z == 0) { Bt = WqT; bias = bq; }
    else if (z == 1) { Bt = WkT; bias = bk; }
    else { Bt = WvT; bias = bv; }

    __shared__ short smem[8192];
    short* As = smem;
    short* Bs = smem + 4096;

    const int tid = threadIdx.x;
    const int lane = tid & 63, w = tid >> 6;
    const int li = lane & 15, g = lane >> 4;
    const int wr = w >> 1, wc = w & 1;
    const int m0 = blockIdx.y * 64, n0 = blockIdx.x * 64;

    f32x4 acc[2][2];
    for (int ra = 0; ra < 2; ++ra)
        for (int cb = 0; cb < 2; ++cb)
            for (int r = 0; r < 4; ++r) acc[ra][cb][r] = 0.f;

#pragma unroll 1
    for (int k0 = 0; k0 < HIDV; k0 += 64) {
#pragma unroll
        for (int j = 0; j < 2; ++j) {
            int c = j * 256 + tid;
            int row = c >> 3, s = c & 7;
            int src = s ^ (row & 7);
            gload16(Abf + (size_t)(m0 + row) * HIDV + k0 + src * 8, As + c * 8);
            gload16(Bt + (size_t)(n0 + row) * HIDV + k0 + src * 8, Bs + c * 8);
        }
        __syncthreads();
#pragma unroll
        for (int c = 0; c < 2; ++c) {
            short8v af[2], bf[2];
#pragma unroll
            for (int ra = 0; ra < 2; ++ra) {
                int row = 32 * wr + 16 * ra + li;
                int chunk = (4 * c + g) ^ (row & 7);
                af[ra] = *reinterpret_cast<const short8v*>(&As[row * 64 + chunk * 8]);
            }
#pragma unroll
            for (int cb = 0; cb < 2; ++cb) {
                int rowb = 32 * wc + 16 * cb + li;
                int chunk = (4 * c + g) ^ (rowb & 7);
                bf[cb] = *reinterpret_cast<const short8v*>(&Bs[rowb * 64 + chunk * 8]);
            }
#pragma unroll
            for (int ra = 0; ra < 2; ++ra)
#pragma unroll
                for (int cb = 0; cb < 2; ++cb)
                    acc[ra][cb] = MFMA16(af[ra], bf[cb], acc[ra][cb]);
        }
        __syncthreads();
    }

    const int h = n0 >> 6;
    const int bidx = m0 >> 9;
    if (z < 2) {
        short* dst = (z == 0) ? qo : ko;
        float sc = (z == 0) ? 1.f : 0.125f;
#pragma unroll
        for (int ra = 0; ra < 2; ++ra)
#pragma unroll
            for (int cb = 0; cb < 2; ++cb) {
                int n = 32 * wc + 16 * cb + li;
                float bv_ = bias[n0 + n];
#pragma unroll
                for (int r = 0; r < 4; ++r) {
                    int m = m0 + 32 * wr + 16 * ra + 4 * g + r;
                    int s = m & 511;
                    dst[(((size_t)bidx * HH + h) * SS + s) * DD + n] =
                        f2bf((acc[ra][cb][r] + bv_) * sc);
                }
            }
    } else {
        short* Cs = smem;
#pragma unroll
        for (int ra = 0; ra < 2; ++ra)
#pragma unroll
            for (int cb = 0; cb < 2; ++cb) {
                int nl = 32 * wc + 16 * cb + li;
                float bv_ = bias[n0 + nl];
#pragma unroll
                for (int r = 0; r < 4; ++r) {
                    int ml = 32 * wr + 16 * ra + 4 * g + r;
                    Cs[nl * 72 + ml] = f2bf(acc[ra][cb][r] + bv_);
                }
            }
        __syncthreads();
        for (int c = tid; c < 512; c += 256) {
            int dl = c >> 3, s8 = (c & 7) * 8;
            short8v vv = *reinterpret_cast<const short8v*>(&Cs[dl * 72 + s8]);
            *reinterpret_cast<short8v*>(
                &vto[(((size_t)bidx * HH + h) * DD + dl) * SS + (m0 & 511) + s8]) = vv;
        }
    }
}

// ---------------- qrelG[bh][512][96] f32 = Q @ lnkb^T via MFMA ----------------
__global__ __launch_bounds__(256) void qrelg_kernel(const short* __restrict__ qb,
                                                    const short* __restrict__ lnkb,
                                                    float* __restrict__ qrelG) {
    const int tid = threadIdx.x;
    const int w = tid >> 6, lane = tid & 63;
    const int li = lane & 15, g = lane >> 4;
    const int bx = blockIdx.x;
    const int bh = bx >> 3, qt = bx & 7;
    const int q0 = qt * 64 + 16 * w;

    const short* base = qb + ((size_t)bh * SS + q0 + li) * DD + 8 * g;
    short8v a0 = *reinterpret_cast<const short8v*>(base);
    short8v a1 = *reinterpret_cast<const short8v*>(base + 32);
#pragma unroll
    for (int ct = 0; ct < 6; ++ct) {
        f32x4 a = {0.f, 0.f, 0.f, 0.f};
        short8v b0 = *reinterpret_cast<const short8v*>(&lnkb[(16 * ct + li) * DD + 8 * g]);
        short8v b1 = *reinterpret_cast<const short8v*>(&lnkb[(16 * ct + li) * DD + 32 + 8 * g]);
        a = MFMA16(a0, b0, a);
        a = MFMA16(a1, b1, a);
#pragma unroll
        for (int r = 0; r < 4; ++r)
            qrelG[((size_t)bh * SS + q0 + 4 * g + r) * 96 + 16 * ct + li] = a[r];
    }
}

// ---------------- qk16: S[bhL][512][512] fp16 = Q @ K^T + mask ----------------
__global__ __launch_bounds__(256, 2) void qk_kernel(
    const short* __restrict__ qb, const short* __restrict__ kb,
    const float* __restrict__ maskp, short* __restrict__ Sbuf, int bh0) {
    __shared__ short Ks[2][64][64];
    __shared__ float maskL[512];

    const int tid = threadIdx.x;
    const int w = tid >> 6, lane = tid & 63;
    const int li = lane & 15, g = lane >> 4;
    const int wr = w >> 1, wc = w & 1;
    const int bx = blockIdx.x;
    const int bhL = bx >> 3, qt = bx & 7;
    const int bh = bh0 + bhL;
    const int b = bh / HH;
    const int q0 = qt * 64;

    const short* kbp = kb + (size_t)bh * SS * DD;
    short* sbp = Sbuf + (size_t)bhL * SS * SS;

#pragma unroll
    for (int j = 0; j < 2; ++j) {
        int c = tid + 256 * j, row = c >> 3, s8 = (c & 7) ^ (row & 7);
        gload16(kbp + (size_t)row * DD + s8 * 8, &Ks[0][0][0] + c * 8);
    }
    for (int i = tid; i < SS; i += 256) maskL[i] = maskp[(size_t)b * SS + i];
    asm volatile("s_waitcnt lgkmcnt(0)" ::: "memory");

    short8v af[2][2];
#pragma unroll
    for (int ra = 0; ra < 2; ++ra) {
        const short* base = qb + ((size_t)bh * SS + q0 + 32 * wr + 16 * ra + li) * DD + 8 * g;
        af[ra][0] = *reinterpret_cast<const short8v*>(base);
        af[ra][1] = *reinterpret_cast<const short8v*>(base + 32);
    }

#pragma unroll
    for (int kt = 0; kt < 8; ++kt) {
        const int cur = kt & 1, nxt = cur ^ 1;
        const int kb0 = kt * 64;

        if (kt < 7) {
#pragma unroll
            for (int j = 0; j < 2; ++j) {
                int c = tid + 256 * j, row = c >> 3, s8 = (c & 7) ^ (row & 7);
                gload16(kbp + (size_t)(kb0 + 64 + row) * DD + s8 * 8, &Ks[nxt][0][0] + c * 8);
            }
            __builtin_amdgcn_sched_barrier(0);
            if (kt == 0) asm volatile("s_waitcnt vmcnt(2)" ::: "memory");
            else         asm volatile("s_waitcnt vmcnt(18)" ::: "memory");
        } else {
            asm volatile("s_waitcnt vmcnt(16)" ::: "memory");
        }
        __builtin_amdgcn_sched_barrier(0);
        __builtin_amdgcn_s_barrier();
        __builtin_amdgcn_sched_barrier(0);

        f32x4 acc[2][2];
#pragma unroll
        for (int ra = 0; ra < 2; ++ra)
#pragma unroll
            for (int cb = 0; cb < 2; ++cb)
                for (int r = 0; r < 4; ++r) acc[ra][cb][r] = 0.f;
#pragma unroll
        for (int c = 0; c < 2; ++c) {
            short8v bf[2];
#pragma unroll
            for (int cb = 0; cb < 2; ++cb) {
                int rowb = 32 * wc + 16 * cb + li;
                int chunk = (4 * c + g) ^ (rowb & 7);
                bf[cb] = *reinterpret_cast<const short8v*>(&Ks[cur][rowb][chunk * 8]);
            }
#pragma unroll
            for (int ra = 0; ra < 2; ++ra)
#pragma unroll
                for (int cb = 0; cb < 2; ++cb)
                    acc[ra][cb] = MFMA16(af[ra][c], bf[cb], acc[ra][cb]);
        }

        // fp16 stores of S + mask
#pragma unroll
        for (int ra = 0; ra < 2; ++ra)
#pragma unroll
            for (int cb = 0; cb < 2; ++cb) {
                const int colk = kb0 + 32 * wc + 16 * cb + li;
                const float m = maskL[colk];
                const int rowb = q0 + 32 * wr + 16 * ra + 4 * g;
#pragma unroll
                for (int r = 0; r < 4; ++r)
                    sbp[(size_t)(rowb + r) * SS + colk] = f2h(acc[ra][cb][r] + m);
            }

        __builtin_amdgcn_s_barrier();
        __builtin_amdgcn_sched_barrier(0);
    }
}

// ---------------- pv2: fused exp+bucket+PV+relV+normalize ----------------
// Block = 64 q-rows of one bh, sweeps all 512 k in 8 tiles. P lives only in LDS.
__global__ __launch_bounds__(256, 2) void pv2_kernel(
    const short* __restrict__ Sbuf, const unsigned char* __restrict__ arc8,
    const float* __restrict__ qrelG, const short* __restrict__ vt,
    const short* __restrict__ lnvT96, float* __restrict__ outp, int bh0) {
    __shared__ short Vs[2][64][64];    // 16.4 KB
    __shared__ short pl[64][72];       // 9.2 KB
    __shared__ float qlds[64][96];     // 24.6 KB
    __shared__ float bucket[64][100];  // 25.6 KB
    __shared__ float rowsumL[64];

    const int tid = threadIdx.x;
    const int w = tid >> 6, lane = tid & 63;
    const int li = lane & 15, g = lane >> 4;
    const int wr = w >> 1, wc = w & 1;
    const int bx = blockIdx.x;
    const int bhL = bx >> 3, qt = bx & 7;
    const int bh = bh0 + bhL;
    const int b = bh / HH, h = bh % HH;
    const int q0 = qt * 64;

    const short* vbp = vt + (size_t)bh * DD * SS;

    // stage V(0)
#pragma unroll
    for (int j = 0; j < 2; ++j) {
        int c = tid + 256 * j, row = c >> 3, s8 = (c & 7) ^ (row & 7);
        gload16(vbp + (size_t)row * SS + s8 * 8, &Vs[0][0][0] + c * 8);
    }
    // stage qrel rows, zero buckets
    {
        const float* qsrc = qrelG + ((size_t)bh * SS + q0) * 96;
        for (int i = tid; i < 64 * 96; i += 256) (&qlds[0][0])[i] = qsrc[i];
    }
    for (int i = tid; i < 64 * 100; i += 256) (&bucket[0][0])[i] = 0.f;

    // exp-phase mapping: thread -> (row, 16 consecutive k)
    const int erow = tid >> 2;
    const int ek0 = (tid & 3) * 16;
    const short* Srow = Sbuf + ((size_t)bhL * SS + q0 + erow) * SS + ek0;
    const unsigned char* Arow = arc8 + ((size_t)b * SS + q0 + erow) * SS + ek0;

    __syncthreads();   // qlds/bucket ready

    f32x4 acc[2][2];
#pragma unroll
    for (int ra = 0; ra < 2; ++ra)
#pragma unroll
        for (int cb = 0; cb < 2; ++cb)
            for (int r = 0; r < 4; ++r) acc[ra][cb][r] = 0.f;

#pragma unroll
    for (int it = 0; it < 8; ++it) {
        const int cur = it & 1, nxt = cur ^ 1;
        const int kb0 = it * 64;

        // stage V(it+1)
        if (it < 7) {
#pragma unroll
            for (int j = 0; j < 2; ++j) {
                int c = tid + 256 * j, row = c >> 3, s8 = (c & 7) ^ (row & 7);
                gload16(vbp + (size_t)row * SS + kb0 + 64 + s8 * 8, &Vs[nxt][0][0] + c * 8);
            }
        }

        // exp phase: 16 elems (S fp16 + arc u8 from global, qrel gather from LDS)
        short8v s0 = *reinterpret_cast<const short8v*>(Srow + kb0);
        short8v s1 = *reinterpret_cast<const short8v*>(Srow + kb0 + 8);
        uint4 a4 = *reinterpret_cast<const uint4*>(Arow + kb0);
        float p[16];
#pragma unroll
        for (int j = 0; j < 16; ++j) {
            const unsigned aw = (j < 4) ? a4.x : (j < 8) ? a4.y : (j < 12) ? a4.z : a4.w;
            const int lab = (aw >> ((j & 3) * 8)) & 255;
            const float sv = h2f((j < 8) ? s0[j] : s1[j - 8]);
            float v = __expf(sv + qlds[erow][lab]);
            p[j] = v;
            unsafeAtomicAdd(&bucket[erow][lab], v);
        }
        short8v pv0, pv1;
#pragma unroll
        for (int j = 0; j < 8; ++j) { pv0[j] = f2bf(p[j]); pv1[j] = f2bf(p[j + 8]); }
        *reinterpret_cast<short8v*>(&pl[erow][ek0]) = pv0;
        *reinterpret_cast<short8v*>(&pl[erow][ek0 + 8]) = pv1;

        __syncthreads();   // pl complete; Vs[cur] landed (drained by this iter's S-load waits)

        // PV MFMA from LDS
#pragma unroll
        for (int c = 0; c < 2; ++c) {
            short8v af[2], bf[2];
#pragma unroll
            for (int ra = 0; ra < 2; ++ra) {
                int row = 32 * wr + 16 * ra + li;
                af[ra] = *reinterpret_cast<const short8v*>(&pl[row][(4 * c + g) * 8]);
            }
#pragma unroll
            for (int cb = 0; cb < 2; ++cb) {
                int rowb = 32 * wc + 16 * cb + li;
                int chunk = (4 * c + g) ^ (rowb & 7);
                bf[cb] = *reinterpret_cast<const short8v*>(&Vs[cur][rowb][chunk * 8]);
            }
#pragma unroll
            for (int ra = 0; ra < 2; ++ra)
#pragma unroll
                for (int cb = 0; cb < 2; ++cb)
                    acc[ra][cb] = MFMA16(af[ra], bf[cb], acc[ra][cb]);
        }

        __syncthreads();   // done reading pl / Vs[cur] before overwrite
    }

    // rowsum from buckets
    if (tid < 64) {
        float s = 0.f;
        for (int l = 0; l < LV; ++l) s += bucket[tid][l];
        rowsumL[tid] = s;
    }
    __syncthreads();

    // relV: acc += bucket(bf16) @ lnvT96  (labels zero-padded to 96)
#pragma unroll
    for (int c = 0; c < 3; ++c) {
        short8v bfr[2], lf[2];
#pragma unroll
        for (int ra = 0; ra < 2; ++ra) {
            int row = 32 * wr + 16 * ra + li;
            f32x4 b0 = *reinterpret_cast<const f32x4*>(&bucket[row][32 * c + 8 * g]);
            f32x4 b1 = *reinterpret_cast<const f32x4*>(&bucket[row][32 * c + 8 * g + 4]);
#pragma unroll
            for (int e = 0; e < 4; ++e) { bfr[ra][e] = f2bf(b0[e]); bfr[ra][e + 4] = f2bf(b1[e]); }
        }
#pragma unroll
        for (int cb = 0; cb < 2; ++cb) {
            int rowb = 32 * wc + 16 * cb + li;
            lf[cb] = *reinterpret_cast<const short8v*>(&lnvT96[rowb * 96 + 32 * c + 8 * g]);
        }
#pragma unroll
        for (int ra = 0; ra < 2; ++ra)
#pragma unroll
            for (int cb = 0; cb < 2; ++cb)
                acc[ra][cb] = MFMA16(bfr[ra], lf[cb], acc[ra][cb]);
    }

    // epilogue: normalize + write
#pragma unroll
    for (int ra = 0; ra < 2; ++ra)
#pragma unroll
        for (int cb = 0; cb < 2; ++cb) {
            int col = 32 * wc + 16 * cb + li;
#pragma unroll
            for (int r = 0; r < 4; ++r) {
                int rowl = 32 * wr + 16 * ra + 4 * g + r;
                outp[((size_t)b * SS + q0 + rowl) * HIDV + h * DD + col] =
                    acc[ra][cb][r] / rowsumL[rowl];
            }
        }
}

// ---------------- launcher ----------------
extern "C" void kernel_launch(void* const* d_in, const int* in_sizes, int n_in,
                              void* d_out, int out_size, void* d_ws, size_t ws_size,
                              hipStream_t stream) {
    const float* hidden = (const float*)d_in[0];
    const float* mask   = (const float*)d_in[1];
    const int*   arc    = (const int*)d_in[2];
    const float* Wq = (const float*)d_in[3];
    const float* bq = (const float*)d_in[4];
    const float* Wk = (const float*)d_in[5];
    const float* bk = (const float*)d_in[6];
    const float* Wv = (const float*)d_in[7];
    const float* bv = (const float*)d_in[8];
    const float* rel_k = (const float*)d_in[9];
    const float* rel_v = (const float*)d_in[10];
    const float* lng_k = (const float*)d_in[11];
    const float* lnb_k = (const float*)d_in[12];
    const float* lng_v = (const float*)d_in[13];
    const float* lnb_v = (const float*)d_in[14];
    float* out = (float*)d_out;

    char* p = (char*)d_ws;
    auto carve = [&](size_t bytes) { char* r = p; p += (bytes + 255) & ~(size_t)255; return r; };
    short* lnkb   = (short*)carve((size_t)96 * DD * 2);
    short* lnvT96 = (short*)carve((size_t)DD * 96 * 2);
    const size_t per = (size_t)BB * HH * SS * DD;
    short* qbuf = (short*)carve(per * 2);
    short* kbuf = (short*)carve(per * 2);
    short* vtb  = (short*)carve(per * 2);
    unsigned char* arc8 = (unsigned char*)carve((size_t)BB * SS * SS);
    char* tail = p;  // aliased region

    // phase-1 residents of tail (dead after qkv_gemm):
    short* hbf  = (short*)tail;
    short* WqT  = hbf + (size_t)BB * SS * HIDV;
    short* WkT  = WqT + (size_t)HIDV * HIDV;
    short* WvT  = WkT + (size_t)HIDV * HIDV;
    // phase-2 residents of tail:
    float* qrelG = (float*)tail;   // 96*512*96*4 = 18.9 MB
    char* tail2 = tail + (((size_t)96 * SS * 96 * 4 + 255) & ~(size_t)255);

    size_t head_used = (size_t)(tail2 - (char*)d_ws);
    int C = 3;
    for (int cand = 96; cand >= 3; cand >>= 1) {
        size_t need = head_used + (size_t)cand * SS * SS * 2;  // Sbuf fp16
        if (need <= ws_size && 96 % cand == 0) { C = cand; break; }
    }
    short* Sbuf = (short*)tail2;

    prep_ln_kernel<<<1, 256, 0, stream>>>(rel_k, rel_v, lng_k, lnb_k, lng_v, lnb_v, lnkb, lnvT96);
    conv_hidden_kernel<<<(BB * SS * HIDV) / 1024, 256, 0, stream>>>(hidden, hbf);
    transw_kernel<<<dim3(24, 24, 3), 256, 0, stream>>>(Wq, Wk, Wv, WqT, WkT, WvT);
    arc8_kernel<<<dim3((BB * SS * SS) / (16 * 256)), 256, 0, stream>>>(arc, arc8);
    qkv_gemm_kernel<<<dim3(HIDV / 64, (BB * SS) / 64, 3), 256, 0, stream>>>(
        hbf, WqT, WkT, WvT, bq, bk, bv, qbuf, kbuf, vtb);
    qrelg_kernel<<<dim3(96 * 8), 256, 0, stream>>>(qbuf, lnkb, qrelG);

    for (int bh0 = 0; bh0 < 96; bh0 += C) {
        qk_kernel<<<dim3(C * 8), 256, 0, stream>>>(qbuf, kbuf, mask, Sbuf, bh0);
        pv2_kernel<<<dim3(C * 8), 256, 0, stream>>>(Sbuf, arc8, qrelG, vtb, lnvT96, out, bh0);
    }
}

// Round 13
// 195.957 us; speedup vs baseline: 1.3852x; 1.3852x over previous
//
#include <hip/hip_runtime.h>
#include <hip/hip_bf16.h>

#define BB 8
#define SS 512
#define HIDV 768
#define HH 12
#define DD 64
#define LV 81

typedef __attribute__((ext_vector_type(8))) short short8v;
typedef __attribute__((ext_vector_type(4))) short short4v;
typedef __attribute__((ext_vector_type(4))) float f32x4;

#define MFMA16(a, b, c) __builtin_amdgcn_mfma_f32_16x16x32_bf16(a, b, c, 0, 0, 0)

__device__ __forceinline__ short f2bf(float f) {
    __hip_bfloat16 h = __float2bfloat16(f);
    return *reinterpret_cast<short*>(&h);
}
__device__ __forceinline__ void gload16(const void* g, void* l) {
    __builtin_amdgcn_global_load_lds((const __attribute__((address_space(1))) void*)g,
                                     (__attribute__((address_space(3))) void*)l, 16, 0, 0);
}

// ---------------- LN tables -> lnkb bf16 [96][64], lnvT bf16 [64][96] ----------------
__global__ __launch_bounds__(256) void prep_ln_kernel(
    const float* __restrict__ rel_k, const float* __restrict__ rel_v,
    const float* __restrict__ gk, const float* __restrict__ bk,
    const float* __restrict__ gv, const float* __restrict__ bv,
    short* __restrict__ lnkb, short* __restrict__ lnvT) {
    __shared__ float ln_lds[2 * LV][DD];
    int t = threadIdx.x;
    if (t < 2 * LV) {
        bool isv = (t >= LV);
        int r = isv ? t - LV : t;
        const float* row = (isv ? rel_v : rel_k) + r * DD;
        const float* g = isv ? gv : gk;
        const float* be = isv ? bv : bk;
        float mu = 0.f;
        for (int d = 0; d < DD; ++d) mu += row[d];
        mu *= (1.f / DD);
        float var = 0.f;
        for (int d = 0; d < DD; ++d) { float x = row[d] - mu; var += x * x; }
        var *= (1.f / DD);
        float rs = rsqrtf(var + 1e-5f);
        for (int d = 0; d < DD; ++d) ln_lds[t][d] = (row[d] - mu) * rs * g[d] + be[d];
    }
    __syncthreads();
    for (int i = t; i < 96 * DD; i += 256) {
        int l = i >> 6, d = i & 63;
        lnkb[i] = (l < LV) ? f2bf(ln_lds[l][d]) : (short)0;
    }
    for (int i = t; i < DD * 96; i += 256) {
        int d = i / 96, ll = i - d * 96;
        lnvT[i] = (ll < LV) ? f2bf(ln_lds[LV + ll][d]) : (short)0;
    }
}

// ---------------- hidden f32 -> bf16 ----------------
__global__ __launch_bounds__(256) void conv_hidden_kernel(const float* __restrict__ in,
                                                          short* __restrict__ out) {
    int i = (blockIdx.x * 256 + threadIdx.x) * 4;
    float4 v = *reinterpret_cast<const float4*>(&in[i]);
    short4v o; o[0] = f2bf(v.x); o[1] = f2bf(v.y); o[2] = f2bf(v.z); o[3] = f2bf(v.w);
    *reinterpret_cast<short4v*>(&out[i]) = o;
}

// ---------------- W [k][n] f32 -> WT [n][k] bf16 (x3 via z) ----------------
__global__ __launch_bounds__(256) void transw_kernel(
    const float* __restrict__ Wq, const float* __restrict__ Wk, const float* __restrict__ Wv,
    short* __restrict__ WqT, short* __restrict__ WkT, short* __restrict__ WvT) {
    const float* W; short* O;
    if (blockIdx.z == 0) { W = Wq; O = WqT; }
    else if (blockIdx.z == 1) { W = Wk; O = WkT; }
    else { W = Wv; O = WvT; }
    __shared__ float tile[32][33];
    int k0 = blockIdx.y * 32, n0 = blockIdx.x * 32;
    int t = threadIdx.x;
    int r = t >> 3, c4 = (t & 7) * 4;
    float4 v = *reinterpret_cast<const float4*>(&W[(size_t)(k0 + r) * HIDV + n0 + c4]);
    tile[r][c4 + 0] = v.x; tile[r][c4 + 1] = v.y; tile[r][c4 + 2] = v.z; tile[r][c4 + 3] = v.w;
    __syncthreads();
    short4v o;
    o[0] = f2bf(tile[c4 + 0][r]); o[1] = f2bf(tile[c4 + 1][r]);
    o[2] = f2bf(tile[c4 + 2][r]); o[3] = f2bf(tile[c4 + 3][r]);
    *reinterpret_cast<short4v*>(&O[(size_t)(n0 + r) * HIDV + k0 + c4]) = o;
}

// ---------------- arc int32 [b][q][k] -> packed u32 arcP [b][k>>2][q] (4 labels/u32) ----------------
__global__ __launch_bounds__(256) void arcpack_kernel(const int* __restrict__ arc,
                                                      unsigned int* __restrict__ arcP) {
    __shared__ unsigned int tbuf[64][129];
    const int tid = threadIdx.x;
    const int b = blockIdx.y;
    const int q0 = blockIdx.x * 64;
    for (int i = tid; i < 64 * 128; i += 256) {
        int r = i >> 7, c4 = i & 127;
        int4 v = *reinterpret_cast<const int4*>(&arc[((size_t)(b * SS) + q0 + r) * SS + 4 * c4]);
        tbuf[r][c4] = (unsigned)(v.x & 255) | ((unsigned)(v.y & 255) << 8) |
                      ((unsigned)(v.z & 255) << 16) | ((unsigned)(v.w & 255) << 24);
    }
    __syncthreads();
    for (int i = tid; i < 128 * 64; i += 256) {
        int k4 = i >> 6, r = i & 63;
        arcP[((size_t)b * 128 + k4) * SS + q0 + r] = tbuf[r][k4];
    }
}

// ---------------- QKV GEMM bf16 MFMA (unchanged, proven) ----------------
__global__ __launch_bounds__(256) void qkv_gemm_kernel(
    const short* __restrict__ Abf,
    const short* __restrict__ WqT, const short* __restrict__ WkT, const short* __restrict__ WvT,
    const float* __restrict__ bq, const float* __restrict__ bk, const float* __restrict__ bv,
    short* __restrict__ qo, short* __restrict__ ko, short* __restrict__ vto) {
    const short* Bt; const float* bias;
    int z = blockIdx.z;
    if (z == 0) { Bt = WqT; bias = bq; }
    else if (z == 1) { Bt = WkT; bias = bk; }
    else { Bt = WvT; bias = bv; }

    __shared__ short smem[8192];
    short* As = smem;
    short* Bs = smem + 4096;

    const int tid = threadIdx.x;
    const int lane = tid & 63, w = tid >> 6;
    const int li = lane & 15, g = lane >> 4;
    const int wr = w >> 1, wc = w & 1;
    const int m0 = blockIdx.y * 64, n0 = blockIdx.x * 64;

    f32x4 acc[2][2];
    for (int ra = 0; ra < 2; ++ra)
        for (int cb = 0; cb < 2; ++cb)
            for (int r = 0; r < 4; ++r) acc[ra][cb][r] = 0.f;

#pragma unroll 1
    for (int k0 = 0; k0 < HIDV; k0 += 64) {
#pragma unroll
        for (int j = 0; j < 2; ++j) {
            int c = j * 256 + tid;
            int row = c >> 3, s = c & 7;
            int src = s ^ (row & 7);
            gload16(Abf + (size_t)(m0 + row) * HIDV + k0 + src * 8, As + c * 8);
            gload16(Bt + (size_t)(n0 + row) * HIDV + k0 + src * 8, Bs + c * 8);
        }
        __syncthreads();
#pragma unroll
        for (int c = 0; c < 2; ++c) {
            short8v af[2], bf[2];
#pragma unroll
            for (int ra = 0; ra < 2; ++ra) {
                int row = 32 * wr + 16 * ra + li;
                int chunk = (4 * c + g) ^ (row & 7);
                af[ra] = *reinterpret_cast<const short8v*>(&As[row * 64 + chunk * 8]);
            }
#pragma unroll
            for (int cb = 0; cb < 2; ++cb) {
                int rowb = 32 * wc + 16 * cb + li;
                int chunk = (4 * c + g) ^ (rowb & 7);
                bf[cb] = *reinterpret_cast<const short8v*>(&Bs[rowb * 64 + chunk * 8]);
            }
#pragma unroll
            for (int ra = 0; ra < 2; ++ra)
#pragma unroll
                for (int cb = 0; cb < 2; ++cb)
                    acc[ra][cb] = MFMA16(af[ra], bf[cb], acc[ra][cb]);
        }
        __syncthreads();
    }

    const int h = n0 >> 6;
    const int bidx = m0 >> 9;
    if (z < 2) {
        short* dst = (z == 0) ? qo : ko;
        float sc = (z == 0) ? 1.f : 0.125f;
#pragma unroll
        for (int ra = 0; ra < 2; ++ra)
#pragma unroll
            for (int cb = 0; cb < 2; ++cb) {
                int n = 32 * wc + 16 * cb + li;
                float bv_ = bias[n0 + n];
#pragma unroll
                for (int r = 0; r < 4; ++r) {
                    int m = m0 + 32 * wr + 16 * ra + 4 * g + r;
                    int s = m & 511;
                    dst[(((size_t)bidx * HH + h) * SS + s) * DD + n] =
                        f2bf((acc[ra][cb][r] + bv_) * sc);
                }
            }
    } else {
        short* Cs = smem;
#pragma unroll
        for (int ra = 0; ra < 2; ++ra)
#pragma unroll
            for (int cb = 0; cb < 2; ++cb) {
                int nl = 32 * wc + 16 * cb + li;
                float bv_ = bias[n0 + nl];
#pragma unroll
                for (int r = 0; r < 4; ++r) {
                    int ml = 32 * wr + 16 * ra + 4 * g + r;
                    Cs[nl * 72 + ml] = f2bf(acc[ra][cb][r] + bv_);
                }
            }
        __syncthreads();
        for (int c = tid; c < 512; c += 256) {
            int dl = c >> 3, s8 = (c & 7) * 8;
            short8v vv = *reinterpret_cast<const short8v*>(&Cs[dl * 72 + s8]);
            *reinterpret_cast<short8v*>(
                &vto[(((size_t)bidx * HH + h) * DD + dl) * SS + (m0 & 511) + s8]) = vv;
        }
    }
}

// ---------------- fused attention v13: r6 structure + pipelined full unroll ----------------
// 256 thr = 4 waves, wave-private (no barriers). Swapped QK: lane owns q=li,
// k=16t+4g+r; P stays in registers. Full unroll; K frags single-buffered with
// early issue (load->use gap = one exp phase); arc/mask register-double-buffered;
// batched LDS gathers; ds_add_f32 buckets (stride 100 to spread banks).
__global__ __launch_bounds__(256, 2) void attn_kernel(
    const short* __restrict__ qb, const short* __restrict__ kb, const short* __restrict__ vt,
    const unsigned int* __restrict__ arcP, const float* __restrict__ maskp,
    const short* __restrict__ lnkb, const short* __restrict__ lnvT,
    float* __restrict__ outp) {
    __shared__ float qlds[4][16][84];     // 21.5 KB
    __shared__ float bucket[4][16][100];  // 25.6 KB (stride 100: rows spread banks)

    const int tid = threadIdx.x;
    const int w = tid >> 6, lane = tid & 63;
    const int li = lane & 15, g = lane >> 4;
    const int bx = blockIdx.x;
    const int b = bx & 7;                 // XCD affinity: all blocks of batch b together
    const int rest = bx >> 3;
    const int h = rest % HH, qt = rest / HH;
    const int bh = b * HH + h;
    const int q0 = qt * 64 + w * 16;

    const short* kbp = kb + (size_t)bh * SS * DD;
    const short* vbp = vt + (size_t)bh * DD * SS;
    const unsigned int* apb = arcP + (size_t)b * 128 * SS;
    const float* mkb = maskp + (size_t)b * SS;

    for (int i = lane; i < 16 * 100; i += 64) (&bucket[w][0][0])[i] = 0.f;

    // Q fragments (B-operand)
    short8v qf0, qf1;
    {
        const short* qrow = qb + ((size_t)bh * SS + q0 + li) * DD + 8 * g;
        qf0 = *reinterpret_cast<const short8v*>(qrow);
        qf1 = *reinterpret_cast<const short8v*>(qrow + 32);
    }

    // qrel tile via MFMA: qlds[w][q-row][label] (wave-private)
#pragma unroll
    for (int ct = 0; ct < 6; ++ct) {
        f32x4 a = {0.f, 0.f, 0.f, 0.f};
        short8v b0 = *reinterpret_cast<const short8v*>(&lnkb[(16 * ct + li) * DD + 8 * g]);
        short8v b1 = *reinterpret_cast<const short8v*>(&lnkb[(16 * ct + li) * DD + 32 + 8 * g]);
        a = MFMA16(qf0, b0, a);
        a = MFMA16(qf1, b1, a);
        if (16 * ct + li < 84)
#pragma unroll
            for (int r = 0; r < 4; ++r) qlds[w][4 * g + r][16 * ct + li] = a[r];
    }

    f32x4 oacc[4];
    for (int t = 0; t < 4; ++t) for (int r = 0; r < 4; ++r) oacc[t][r] = 0.f;

    // pipeline state: K frags (single-buffered, early-issued), arc/mask (dbuf)
    short8v kf[8];
    unsigned int a_[2][4];
    float4 m_[2][4];
#pragma unroll
    for (int t = 0; t < 4; ++t) {
        const short* kr = kbp + (size_t)(16 * t + li) * DD + 8 * g;
        kf[2 * t] = *reinterpret_cast<const short8v*>(kr);
        kf[2 * t + 1] = *reinterpret_cast<const short8v*>(kr + 32);
        a_[0][t] = apb[(size_t)(4 * t + g) * SS + q0 + li];
        m_[0][t] = *reinterpret_cast<const float4*>(&mkb[16 * t + 4 * g]);
    }

#pragma unroll
    for (int kt = 0; kt < 8; ++kt) {
        const int cur = kt & 1, nxt = cur ^ 1;
        const int kb0 = kt * 64;

        // 1. QK^T consumes kf (K pre-scaled 0.125); C[k=16t+4g+r][q=li]
        f32x4 sacc[4];
#pragma unroll
        for (int t = 0; t < 4; ++t) {
            f32x4 a = {0.f, 0.f, 0.f, 0.f};
            a = MFMA16(kf[2 * t], qf0, a);
            a = MFMA16(kf[2 * t + 1], qf1, a);
            sacc[t] = a;
        }

        // 2. early-issue next tile's K/arc/mask (consumed after the exp phase)
        if (kt < 7) {
#pragma unroll
            for (int t = 0; t < 4; ++t) {
                const short* kr = kbp + (size_t)(kb0 + 64 + 16 * t + li) * DD + 8 * g;
                kf[2 * t] = *reinterpret_cast<const short8v*>(kr);
                kf[2 * t + 1] = *reinterpret_cast<const short8v*>(kr + 32);
                a_[nxt][t] = apb[(size_t)((kt + 1) * 16 + 4 * t + g) * SS + q0 + li];
                m_[nxt][t] = *reinterpret_cast<const float4*>(&mkb[kb0 + 64 + 16 * t + 4 * g]);
            }
        }

        // 3. batched gather (4 independent ds_reads per t) + exp
        float p[16];
#pragma unroll
        for (int t = 0; t < 4; ++t) {
            const unsigned int a4 = a_[cur][t];
            float qv0 = qlds[w][li][a4 & 255];
            float qv1 = qlds[w][li][(a4 >> 8) & 255];
            float qv2 = qlds[w][li][(a4 >> 16) & 255];
            float qv3 = qlds[w][li][a4 >> 24];
            p[4 * t + 0] = __expf(sacc[t][0] + qv0 + m_[cur][t].x);
            p[4 * t + 1] = __expf(sacc[t][1] + qv1 + m_[cur][t].y);
            p[4 * t + 2] = __expf(sacc[t][2] + qv2 + m_[cur][t].z);
            p[4 * t + 3] = __expf(sacc[t][3] + qv3 + m_[cur][t].w);
        }

        // 4. HW LDS atomics (ds_add_f32)
#pragma unroll
        for (int t = 0; t < 4; ++t) {
            const unsigned int a4 = a_[cur][t];
            unsafeAtomicAdd(&bucket[w][li][a4 & 255], p[4 * t + 0]);
            unsafeAtomicAdd(&bucket[w][li][(a4 >> 8) & 255], p[4 * t + 1]);
            unsafeAtomicAdd(&bucket[w][li][(a4 >> 16) & 255], p[4 * t + 2]);
            unsafeAtomicAdd(&bucket[w][li][a4 >> 24], p[4 * t + 3]);
        }

        // 5. pack P and PV (V slot-permuted loads, as verified in r6)
        short8v pfrag[2];
#pragma unroll
        for (int t = 0; t < 4; ++t)
#pragma unroll
            for (int r = 0; r < 4; ++r) pfrag[t >> 1][4 * (t & 1) + r] = f2bf(p[4 * t + r]);
#pragma unroll
        for (int dt = 0; dt < 2; ++dt) {
#pragma unroll
            for (int t2 = 0; t2 < 4; ++t2) {
                const short* vr = vbp + (size_t)(16 * t2 + li) * SS + kb0 + 32 * dt + 4 * g;
                short4v v0 = *reinterpret_cast<const short4v*>(vr);
                short4v v1 = *reinterpret_cast<const short4v*>(vr + 16);
                short8v vf;
                vf[0] = v0[0]; vf[1] = v0[1]; vf[2] = v0[2]; vf[3] = v0[3];
                vf[4] = v1[0]; vf[5] = v1[1]; vf[6] = v1[2]; vf[7] = v1[3];
                oacc[t2] = MFMA16(pfrag[dt], vf, oacc[t2]);
            }
        }
    }

    // rowsum for q=li from buckets (off the critical path): lane sums cols [24g, 24g+24)
    float lsum = 0.f;
#pragma unroll
    for (int j = 0; j < 24; ++j) {
        int c = 24 * g + j;
        lsum += (c < 81) ? bucket[w][li][c] : 0.f;
    }
    lsum += __shfl_xor(lsum, 16);
    lsum += __shfl_xor(lsum, 32);
    float inv = 1.f / lsum;
    float invr[4];
#pragma unroll
    for (int r = 0; r < 4; ++r) invr[r] = __shfl(inv, 4 * g + r);

    // rel-V: racc = bucket @ lnvT  (labels zero-padded to 96)
    f32x4 racc[4];
    for (int t = 0; t < 4; ++t) for (int r = 0; r < 4; ++r) racc[t][r] = 0.f;
#pragma unroll
    for (int c = 0; c < 3; ++c) {
        f32x4 b0 = *reinterpret_cast<const f32x4*>(&bucket[w][li][8 * g + 32 * c]);
        f32x4 b1 = *reinterpret_cast<const f32x4*>(&bucket[w][li][8 * g + 32 * c + 4]);
        short8v bfr;
        bfr[0] = f2bf(b0[0]); bfr[1] = f2bf(b0[1]); bfr[2] = f2bf(b0[2]); bfr[3] = f2bf(b0[3]);
        bfr[4] = f2bf(b1[0]); bfr[5] = f2bf(b1[1]); bfr[6] = f2bf(b1[2]); bfr[7] = f2bf(b1[3]);
#pragma unroll
        for (int t2 = 0; t2 < 4; ++t2) {
            short8v lf = *reinterpret_cast<const short8v*>(
                &lnvT[(16 * t2 + li) * 96 + 8 * g + 32 * c]);
            racc[t2] = MFMA16(bfr, lf, racc[t2]);
        }
    }

    // write: C[q=4g+r][d=16t2+li]
#pragma unroll
    for (int t2 = 0; t2 < 4; ++t2)
#pragma unroll
        for (int r = 0; r < 4; ++r) {
            int row = q0 + 4 * g + r;
            outp[((size_t)b * SS + row) * HIDV + h * DD + 16 * t2 + li] =
                (oacc[t2][r] + racc[t2][r]) * invr[r];
        }
}

// ---------------- launcher ----------------
extern "C" void kernel_launch(void* const* d_in, const int* in_sizes, int n_in,
                              void* d_out, int out_size, void* d_ws, size_t ws_size,
                              hipStream_t stream) {
    const float* hidden = (const float*)d_in[0];
    const float* mask   = (const float*)d_in[1];
    const int*   arc    = (const int*)d_in[2];
    const float* Wq = (const float*)d_in[3];
    const float* bq = (const float*)d_in[4];
    const float* Wk = (const float*)d_in[5];
    const float* bk = (const float*)d_in[6];
    const float* Wv = (const float*)d_in[7];
    const float* bv = (const float*)d_in[8];
    const float* rel_k = (const float*)d_in[9];
    const float* rel_v = (const float*)d_in[10];
    const float* lng_k = (const float*)d_in[11];
    const float* lnb_k = (const float*)d_in[12];
    const float* lng_v = (const float*)d_in[13];
    const float* lnb_v = (const float*)d_in[14];
    float* out = (float*)d_out;

    char* p = (char*)d_ws;
    auto carve = [&](size_t bytes) { char* r = p; p += (bytes + 255) & ~(size_t)255; return r; };
    short* lnkb = (short*)carve((size_t)96 * DD * 2);
    short* lnvT = (short*)carve((size_t)DD * 96 * 2);
    short* hbf  = (short*)carve((size_t)BB * SS * HIDV * 2);
    short* WqT  = (short*)carve((size_t)HIDV * HIDV * 2);
    short* WkT  = (short*)carve((size_t)HIDV * HIDV * 2);
    short* WvT  = (short*)carve((size_t)HIDV * HIDV * 2);
    const size_t per = (size_t)BB * HH * SS * DD;
    short* qbuf = (short*)carve(per * 2);
    short* kbuf = (short*)carve(per * 2);
    short* vtb  = (short*)carve(per * 2);
    unsigned int* arcP = (unsigned int*)carve((size_t)BB * 128 * SS * 4);

    prep_ln_kernel<<<1, 256, 0, stream>>>(rel_k, rel_v, lng_k, lnb_k, lng_v, lnb_v, lnkb, lnvT);
    conv_hidden_kernel<<<(BB * SS * HIDV) / 1024, 256, 0, stream>>>(hidden, hbf);
    transw_kernel<<<dim3(24, 24, 3), 256, 0, stream>>>(Wq, Wk, Wv, WqT, WkT, WvT);
    arcpack_kernel<<<dim3(8, BB), 256, 0, stream>>>(arc, arcP);
    qkv_gemm_kernel<<<dim3(HIDV / 64, (BB * SS) / 64, 3), 256, 0, stream>>>(
        hbf, WqT, WkT, WvT, bq, bk, bv, qbuf, kbuf, vtb);
    attn_kernel<<<dim3(BB * HH * 8), 256, 0, stream>>>(
        qbuf, kbuf, vtb, arcP, mask, lnkb, lnvT, out);
}